// Round 2
// baseline (1053.408 us; speedup 1.0000x reference)
//
#include <hip/hip_runtime.h>

// ReLU_Feat_Posenc: bilinear gather (512x512x100) + posenc(16 freq) + MLP 166->128x4->3
// R5: persistent-weight k_main. R1 lesson: occupancy 44->87% bought only 6% => a shared
//     throughput path was saturated: per-tile weight reloads (4.6 GB L2 traffic, and a
//     ~300cyc A-load stall after EVERY barrier, every layer -- loads can't be hoisted
//     across s_barrier). Fix: 512 persistent blocks x 32 tiles (TP=64), all MFMA
//     A-fragments (140 VGPR) loaded ONCE per block; bias added at epilogue (off the
//     critical path); W4 packed f16 (12 coalesced loads/tile, was 96 scattered);
//     sorted[] prefetched one tile ahead; {weights,feat,hist} fused into k_prep.
//     Occupancy drops to 2 waves/SIMD -- intentional: latency source removed instead.

#define GN    512
#define CELL  112   // padded f16 feature vector per grid cell (224 B)
#define STR0  184   // LDS X stride (f16), row = 368 B (16B-aligned)
#define STR1  136   // LDS G stride (f16), row = 272 B
#define TP    64    // points per tile
#define NTILES 32   // tiles per persistent block
#define NBLK  512   // persistent blocks (2 per CU)

// wt fragment-order offsets (f16 elems)
#define WOFF1 22528
#define WOFF2 38912
#define WOFF3 55296
#define W4OFF 71680  // packed W4: [qt 0..3][kk 0..31][e 0..2] f16 (384 elems)

typedef _Float16 half8  __attribute__((ext_vector_type(8)));
typedef _Float16 half4v __attribute__((ext_vector_type(4)));
typedef float    f4     __attribute__((ext_vector_type(4)));
typedef float    f16v   __attribute__((ext_vector_type(16)));

// ws layout (bytes):
//   0         wt fragment-order f16 (+ packed W4) (reserve 147456)
//   147456    hist    int[16384]
//   212992    binoff  int[16384]
//   278528    bsum    int[64]
//   278784    bbase   int[64]
//   294912    sorted  float4[1048576] (16 MB)
//   17072128  feat16  [512*512][112] f16 (58.7 MB)   total ~75.8 MB

// ---------- fused prep: weights+W4 pack | feat f32->f16 | hist ----------
__global__ __launch_bounds__(256) void k_prep(
    const float* __restrict__ W0, const float* __restrict__ W1,
    const float* __restrict__ W2, const float* __restrict__ W3,
    const float* __restrict__ W4, _Float16* __restrict__ wt,
    const float* __restrict__ F, _Float16* __restrict__ fout,
    const float* __restrict__ UV, int* __restrict__ hist) {
  int b = blockIdx.x;
  if (b < 282) {                     // ---- weights into MFMA-fragment order ----
    int t = b * 256 + threadIdx.x;
    if (t >= 72064) return;
    float v;
    if (t < 22528) {                 // L0 frags: ((ot*11+ks)*64+l)*8+j
      int j = t & 7, l = (t >> 3) & 63, g = t >> 9;
      int ks = g % 11;
      int ot = g / 11;
      int k = 16 * ks + 8 * (l >> 5) + j;
      int n = ot * 32 + (l & 31);
      if (k < 100)      v = W0[(66 + k) * 128 + n];
      else if (k < 166) v = W0[(k - 100) * 128 + n];
      else              v = 0.0f;
    } else if (t < 71680) {          // L1-3 frags
      int u = t - 22528;
      int layer = u >> 14, r = u & 16383;
      int j = r & 7, l = (r >> 3) & 63, ks = (r >> 9) & 7, ot = r >> 12;
      int k = 16 * ks + 8 * (l >> 5) + j;
      int n = ot * 32 + (l & 31);
      const float* W = (layer == 0) ? W1 : (layer == 1) ? W2 : W3;
      v = W[k * 128 + n];
    } else {                         // packed W4: wt[W4OFF + qt*96 + kk*3 + e]
      int u2 = t - 71680;            // 0..383
      int qt = u2 / 96, r = u2 - 96 * qt;
      int kk = r / 3, e = r - 3 * kk;
      v = W4[(qt * 32 + kk) * 3 + e];
    }
    wt[t] = (_Float16)v;
  } else if (b < 282 + 28672) {      // ---- features f32 -> padded f16 ----
    int e = (b - 282) * 256 + threadIdx.x;
    int cell = e / 28, j4 = e - cell * 28;
    half4v o;
    if (j4 < 25) {
      f4 f = *(const f4*)(F + (size_t)cell * 100 + j4 * 4);
      o[0] = (_Float16)f[0]; o[1] = (_Float16)f[1];
      o[2] = (_Float16)f[2]; o[3] = (_Float16)f[3];
    } else {
      o[0] = o[1] = o[2] = o[3] = (_Float16)0.0f;
    }
    *(half4v*)(fout + (size_t)cell * CELL + j4 * 4) = o;
  } else if (hist != nullptr) {      // ---- histogram (hist pre-zeroed by memset) ----
    int i = (b - (282 + 28672)) * 256 + threadIdx.x;
    float2 uv = ((const float2*)UV)[i];
    int iU0 = (int)floorf(511.0f * uv.x);
    int iV0 = (int)floorf(511.0f * uv.y);
    atomicAdd(&hist[iU0 * 32 + (iV0 >> 4)], 1);
  }
}

__device__ __forceinline__ int point_bin(float U, float V) {
  int iU0 = (int)floorf(511.0f * U);
  int iV0 = (int)floorf(511.0f * V);
  return iU0 * 32 + (iV0 >> 4);
}

__global__ __launch_bounds__(256) void k_scanA(const int* __restrict__ hist,
                                               int* __restrict__ binoff,
                                               int* __restrict__ bsum) {
  __shared__ int s[256];
  int t = threadIdx.x, g = blockIdx.x * 256 + t;   // 64 blocks
  int v = hist[g];
  s[t] = v;
  __syncthreads();
  for (int d = 1; d < 256; d <<= 1) {
    int x = (t >= d) ? s[t - d] : 0;
    __syncthreads();
    s[t] += x;
    __syncthreads();
  }
  binoff[g] = s[t] - v;
  if (t == 255) bsum[blockIdx.x] = s[t];
}

__global__ __launch_bounds__(64) void k_scanB(const int* __restrict__ bsum,
                                              int* __restrict__ bbase) {
  __shared__ int s[64];
  int t = threadIdx.x;
  int v = bsum[t];
  s[t] = v;
  __syncthreads();
  for (int d = 1; d < 64; d <<= 1) {
    int x = (t >= d) ? s[t - d] : 0;
    __syncthreads();
    s[t] += x;
    __syncthreads();
  }
  bbase[t] = s[t] - v;
}

__global__ __launch_bounds__(256) void k_scatter(const float* __restrict__ UV,
                                                 int* __restrict__ binoff,
                                                 const int* __restrict__ bbase,
                                                 float4* __restrict__ sorted) {
  int i = blockIdx.x * 256 + threadIdx.x;     // 4096 blocks
  float2 uv = ((const float2*)UV)[i];
  int bin = point_bin(uv.x, uv.y);
  int pos = atomicAdd(&binoff[bin], 1) + bbase[bin >> 8];
  sorted[pos] = make_float4(uv.x, uv.y, __int_as_float(i), 0.0f);
}

// K=128 layer with PRELOADED A-fragments (persistent regs). Bias at epilogue.
__device__ __forceinline__ void layerP(const half8 (&A)[8],
    const _Float16* Gin, _Float16* Gout, const float* __restrict__ bp,
    int nl, int kh, int ot) {
  f4 bf[4];
#pragma unroll
  for (int g = 0; g < 4; ++g)        // issued first, used after MFMA chain -> hidden
    bf[g] = *(const f4*)(bp + ot * 32 + 4 * kh + 8 * g);
  f16v a0, a1;
#pragma unroll
  for (int r = 0; r < 16; ++r) { a0[r] = 0.f; a1[r] = 0.f; }
#pragma unroll
  for (int ks = 0; ks < 8; ++ks) {
    half8 B0 = *(const half8*)(Gin + nl * STR1 + ks * 16 + kh * 8);
    half8 B1 = *(const half8*)(Gin + (32 + nl) * STR1 + ks * 16 + kh * 8);
    a0 = __builtin_amdgcn_mfma_f32_32x32x16_f16(A[ks], B0, a0, 0, 0, 0);
    a1 = __builtin_amdgcn_mfma_f32_32x32x16_f16(A[ks], B1, a1, 0, 0, 0);
  }
#pragma unroll
  for (int g = 0; g < 4; ++g) {
    half4v h0, h1;
#pragma unroll
    for (int i = 0; i < 4; ++i) {
      float z0 = a0[4 * g + i] + bf[g][i]; z0 = fmaxf(z0, 0.01f * z0);
      float z1 = a1[4 * g + i] + bf[g][i]; z1 = fmaxf(z1, 0.01f * z1);
      h0[i] = (_Float16)z0; h1[i] = (_Float16)z1;
    }
    int col = ot * 32 + 4 * kh + 8 * g;
    *(half4v*)(Gout + nl * STR1 + col) = h0;
    *(half4v*)(Gout + (32 + nl) * STR1 + col) = h1;
  }
}

// MODE: 1 = f16 features, unsorted; 2 = f16 + sorted
template <int MODE>
__global__ __launch_bounds__(256, 2) void k_main(
    const float* __restrict__ UV, const float4* __restrict__ sorted,
    const _Float16* __restrict__ wt, const _Float16* __restrict__ feat16,
    const float* __restrict__ b0, const float* __restrict__ b1,
    const float* __restrict__ b2, const float* __restrict__ b3,
    const float* __restrict__ b4, float* __restrict__ out) {
  __shared__ _Float16 bufA[TP * STR0] __attribute__((aligned(16)));  // 23552 B
  __shared__ _Float16 bufB[TP * STR1] __attribute__((aligned(16)));  // 17408 B
  const int t = threadIdx.x;
  const int lane = t & 63;
  const int q = t >> 6;        // wave id = out-quarter ot
  const int nl = lane & 31;
  const int kh = lane >> 5;
  const int ot = q;
  const int p = lane;          // point within tile

  // ---- persistent weight fragments: loaded ONCE per block (140 VGPR) ----
  half8 A0[11], A1[8], A2[8], A3[8];
#pragma unroll
  for (int ks = 0; ks < 11; ++ks)
    A0[ks] = *(const half8*)(wt + ((ot * 11 + ks) * 64 + lane) * 8);
#pragma unroll
  for (int ks = 0; ks < 8; ++ks) {
    A1[ks] = *(const half8*)(wt + WOFF1 + ((ot * 8 + ks) * 64 + lane) * 8);
    A2[ks] = *(const half8*)(wt + WOFF2 + ((ot * 8 + ks) * 64 + lane) * 8);
    A3[ks] = *(const half8*)(wt + WOFF3 + ((ot * 8 + ks) * 64 + lane) * 8);
  }

  float4 pref;
  if constexpr (MODE == 2) pref = sorted[(size_t)blockIdx.x * NTILES * TP + p];

  for (int it = 0; it < NTILES; ++it) {
    const int ti = blockIdx.x * NTILES + it;
    float U, V;
    int oidx;
    if constexpr (MODE == 2) {
      U = pref.x; V = pref.y; oidx = __float_as_int(pref.z);
    } else {
      oidx = ti * TP + p;
      float2 uv = ((const float2*)UV)[oidx];
      U = uv.x; V = uv.y;
    }

    // ---------------- posenc (cols 100..165) + pad zero + oidx stash --------
    if (q == 0) {
      bufA[p * STR0 + 100] = (_Float16)U;
      bufA[p * STR0 + 101] = (_Float16)V;
#pragma unroll
      for (int c = 166; c < 176; ++c) bufA[p * STR0 + c] = (_Float16)0.0f;
      *(int*)&bufB[p * STR1 + 128] = oidx;   // survives: layers write cols 0..127
    }
    const float inv2pi = 0.15915494309189535f;
    const float twopi  = 6.283185307179586f;
#pragma unroll
    for (int fi = 0; fi < 4; ++fi) {
      int f = 4 * q + fi;
      float kk = (float)(1 << f);
      float ru = kk * U * inv2pi; ru -= floorf(ru);
      float rv = kk * V * inv2pi; rv -= floorf(rv);
      float su = __sinf(ru * twopi), cu = __cosf(ru * twopi);
      float sv = __sinf(rv * twopi), cv = __cosf(rv * twopi);
      int cbase = p * STR0 + 102 + 4 * f;
      bufA[cbase + 0] = (_Float16)su;
      bufA[cbase + 1] = (_Float16)sv;
      bufA[cbase + 2] = (_Float16)cu;
      bufA[cbase + 3] = (_Float16)cv;
    }

    // ---------------- bilinear gather (cols 0..99) ----------------
    {
      float iu = 511.0f * U, iv = 511.0f * V;
      float fu0 = floorf(iu), fv0 = floorf(iv);
      int iU0 = (int)fu0, iV0 = (int)fv0;
      int iU1 = (int)ceilf(iu), iV1 = (int)ceilf(iv);
      float fu = iu - fu0, fv = iv - fv0;
      float w00 = (1.f - fu) * (1.f - fv);
      float w10 = fu * (1.f - fv);
      float w01 = (1.f - fu) * fv;
      float w11 = fu * fv;
      int j0 = 3 * q;
      int j1 = (q == 3) ? 13 : 3 * q + 3;   // chunks {0-2}{3-5}{6-8}{9-12}
      const half8* c00 = (const half8*)(feat16 + (size_t)(iU0 * GN + iV0) * CELL);
      const half8* c01 = (const half8*)(feat16 + (size_t)(iU0 * GN + iV1) * CELL);
      const half8* c10 = (const half8*)(feat16 + (size_t)(iU1 * GN + iV0) * CELL);
      const half8* c11 = (const half8*)(feat16 + (size_t)(iU1 * GN + iV1) * CELL);
      _Float16 h00 = (_Float16)w00, h01 = (_Float16)w01;
      _Float16 h10 = (_Float16)w10, h11 = (_Float16)w11;
      half8 v00, v01, v10, v11;
#pragma unroll
      for (int e = 0; e < 8; ++e) { v00[e]=h00; v01[e]=h01; v10[e]=h10; v11[e]=h11; }
      for (int j = j0; j < j1; ++j) {
        half8 a = c00[j], b = c01[j], c = c10[j], d = c11[j];
        half8 o = a * v00 + b * v01 + c * v10 + d * v11;  // v_pk_fma_f16
        if (j < 12) {
          *(half8*)&bufA[p * STR0 + 8 * j] = o;
        } else {
          half4v o4; o4[0]=o[0]; o4[1]=o[1]; o4[2]=o[2]; o4[3]=o[3];
          *(half4v*)&bufA[p * STR0 + 96] = o4;
        }
      }
    }

    // prefetch next tile's sorted entry (independent -> hidden under MLP)
    if constexpr (MODE == 2) {
      int tn = (it + 1 < NTILES) ? ti + 1 : ti;
      pref = sorted[(size_t)tn * TP + p];
    }
    __syncthreads();

    // ---------------- layer 0: K=176 (11 ksteps), bufA(STR0) -> bufB --------
    {
      f4 bf[4];
#pragma unroll
      for (int g = 0; g < 4; ++g)
        bf[g] = *(const f4*)(b0 + ot * 32 + 4 * kh + 8 * g);
      f16v a0, a1;
#pragma unroll
      for (int r = 0; r < 16; ++r) { a0[r] = 0.f; a1[r] = 0.f; }
#pragma unroll
      for (int ks = 0; ks < 11; ++ks) {
        half8 B0 = *(const half8*)&bufA[nl * STR0 + ks * 16 + kh * 8];
        half8 B1 = *(const half8*)&bufA[(32 + nl) * STR0 + ks * 16 + kh * 8];
        a0 = __builtin_amdgcn_mfma_f32_32x32x16_f16(A0[ks], B0, a0, 0, 0, 0);
        a1 = __builtin_amdgcn_mfma_f32_32x32x16_f16(A0[ks], B1, a1, 0, 0, 0);
      }
#pragma unroll
      for (int g = 0; g < 4; ++g) {
        half4v h0, h1;
#pragma unroll
        for (int i = 0; i < 4; ++i) {
          float z0 = a0[4 * g + i] + bf[g][i]; z0 = fmaxf(z0, 0.01f * z0);
          float z1 = a1[4 * g + i] + bf[g][i]; z1 = fmaxf(z1, 0.01f * z1);
          h0[i] = (_Float16)z0; h1[i] = (_Float16)z1;
        }
        int col = ot * 32 + 4 * kh + 8 * g;
        *(half4v*)&bufB[nl * STR1 + col] = h0;
        *(half4v*)&bufB[(32 + nl) * STR1 + col] = h1;
      }
    }
    __syncthreads();
    layerP(A1, bufB, bufA, b1, nl, kh, ot);  __syncthreads();  // L1
    layerP(A2, bufA, bufB, b2, nl, kh, ot);  __syncthreads();  // L2
    layerP(A3, bufB, bufA, b3, nl, kh, ot);  __syncthreads();  // L3

    // ---------------- layer 4: 128 -> 3, 4 threads/point, packed f16 W4 -----
    {
      int pp = t >> 2, qt = t & 3;
      const _Float16* h4 = &bufA[pp * STR1 + qt * 32];
      const _Float16* w4 = wt + W4OFF + qt * 96;
      float y0 = 0.f, y1 = 0.f, y2 = 0.f;
#pragma unroll
      for (int c = 0; c < 4; ++c) {
        half8 hv = *(const half8*)(h4 + 8 * c);
        half8 wa = *(const half8*)(w4 + c * 24);
        half8 wb = *(const half8*)(w4 + c * 24 + 8);
        half8 wc = *(const half8*)(w4 + c * 24 + 16);
        _Float16 wf[24];
        *(half8*)&wf[0] = wa; *(half8*)&wf[8] = wb; *(half8*)&wf[16] = wc;
#pragma unroll
        for (int e8 = 0; e8 < 8; ++e8) {
          float vf = (float)hv[e8];
          y0 += vf * (float)wf[e8 * 3 + 0];
          y1 += vf * (float)wf[e8 * 3 + 1];
          y2 += vf * (float)wf[e8 * 3 + 2];
        }
      }
      y0 += __shfl_xor(y0, 1); y0 += __shfl_xor(y0, 2);
      y1 += __shfl_xor(y1, 1); y1 += __shfl_xor(y1, 2);
      y2 += __shfl_xor(y2, 1); y2 += __shfl_xor(y2, 2);
      if (qt == 0) {
        int op;
        if constexpr (MODE == 2) op = *(const int*)&bufB[pp * STR1 + 128];
        else                     op = ti * TP + pp;
        out[(size_t)op * 3 + 0] = y0 + b4[0];
        out[(size_t)op * 3 + 1] = y1 + b4[1];
        out[(size_t)op * 3 + 2] = y2 + b4[2];
      }
    }
    __syncthreads();   // bufA/bufB reused by next tile's front-end
  }
}

extern "C" void kernel_launch(void* const* d_in, const int* in_sizes, int n_in,
                              void* d_out, int out_size, void* d_ws, size_t ws_size,
                              hipStream_t stream) {
  const float* UV  = (const float*)d_in[0];
  const float* FEA = (const float*)d_in[1];
  const float* W0  = (const float*)d_in[2];
  const float* b0  = (const float*)d_in[3];
  const float* W1  = (const float*)d_in[4];
  const float* b1  = (const float*)d_in[5];
  const float* W2  = (const float*)d_in[6];
  const float* b2  = (const float*)d_in[7];
  const float* W3  = (const float*)d_in[8];
  const float* b3  = (const float*)d_in[9];
  const float* W4  = (const float*)d_in[10];
  const float* b4  = (const float*)d_in[11];
  float* out = (float*)d_out;

  char* ws = (char*)d_ws;
  _Float16* wt = (_Float16*)ws;
  int*    hist   = (int*)(ws + 147456);
  int*    binoff = (int*)(ws + 212992);
  int*    bsum   = (int*)(ws + 278528);
  int*    bbase  = (int*)(ws + 278784);
  float4* sorted = (float4*)(ws + 294912);
  _Float16* f16s = (_Float16*)(ws + 17072128);
  _Float16* f16u = (_Float16*)(ws + 147456);

  const size_t featBytes = (size_t)GN * GN * CELL * 2ull;   // 58,720,256
  const size_t needSort  = 17072128ull + featBytes;          // ~75.8 MB

  if (ws_size >= needSort) {
    hipMemsetAsync(hist, 0, 65536, stream);
    k_prep<<<282 + 28672 + 4096, 256, 0, stream>>>(W0, W1, W2, W3, W4, wt,
                                                   FEA, f16s, UV, hist);
    k_scanA<<<64, 256, 0, stream>>>(hist, binoff, bsum);
    k_scanB<<<1, 64, 0, stream>>>(bsum, bbase);
    k_scatter<<<4096, 256, 0, stream>>>(UV, binoff, bbase, sorted);
    k_main<2><<<NBLK, 256, 0, stream>>>(UV, sorted, wt, f16s,
                                        b0, b1, b2, b3, b4, out);
  } else {
    k_prep<<<282 + 28672, 256, 0, stream>>>(W0, W1, W2, W3, W4, wt,
                                            FEA, f16u, UV, nullptr);
    k_main<1><<<NBLK, 256, 0, stream>>>(UV, nullptr, wt, f16u,
                                        b0, b1, b2, b3, b4, out);
  }
}

// Round 3
// 500.756 us; speedup vs baseline: 2.1036x; 2.1036x over previous
//
#include <hip/hip_runtime.h>

// ReLU_Feat_Posenc: bilinear gather (512x512x100) + posenc(16 freq) + MLP 166->128x4->3
// R6: back to many small blocks (locality = sliding dispatch window; R5's persistent
//     spans thrashed L2: FETCH 118MB->1.06GB). TP=64, 16384 blocks, launch_bounds(256,4):
//     spend VGPRs (32 -> ~120) on an A-fragment register pipeline -- R4's VGPR=32 forced
//     per-kstep L2-latency weight stalls (the unexplained 50% idle). A0 loaded before FE;
//     A(L+1) prefetched mid-MFMA-loop of layer L (liveness-staggered). Bias at epilogue
//     (zero-init acc: first MFMA no longer waits on a global load). v_sin/v_cos direct
//     on pre-reduced revolutions. Packed-f16 W4. Fused prep kernel.

#define GN    512
#define CELL  112   // padded f16 feature vector per grid cell (224 B)
#define STR0  184   // LDS X stride (f16), row = 368 B (16B-aligned)
#define STR1  136   // LDS G stride (f16), row = 272 B
#define TP    64    // points per tile

// wt fragment-order offsets (f16 elems)
#define WOFF1 22528
#define WOFF2 38912
#define WOFF3 55296
#define W4OFF 71680  // packed W4: [qt 0..3][kk 0..31][e 0..2] f16 (384 elems)

typedef _Float16 half8  __attribute__((ext_vector_type(8)));
typedef _Float16 half4v __attribute__((ext_vector_type(4)));
typedef float    f4     __attribute__((ext_vector_type(4)));
typedef float    f16v   __attribute__((ext_vector_type(16)));

// ws layout (bytes):
//   0         wt fragment-order f16 (+ packed W4) (reserve 147456)
//   147456    hist    int[16384]
//   212992    binoff  int[16384]
//   278528    bsum    int[64]
//   278784    bbase   int[64]
//   294912    sorted  float4[1048576] (16 MB)
//   17072128  feat16  [512*512][112] f16 (58.7 MB)   total ~75.8 MB

// ---------- fused prep: weights+W4 pack | feat f32->f16 | hist ----------
__global__ __launch_bounds__(256) void k_prep(
    const float* __restrict__ W0, const float* __restrict__ W1,
    const float* __restrict__ W2, const float* __restrict__ W3,
    const float* __restrict__ W4, _Float16* __restrict__ wt,
    const float* __restrict__ F, _Float16* __restrict__ fout,
    const float* __restrict__ UV, int* __restrict__ hist) {
  int b = blockIdx.x;
  if (b < 282) {                     // ---- weights into MFMA-fragment order ----
    int t = b * 256 + threadIdx.x;
    if (t >= 72064) return;
    float v;
    if (t < 22528) {                 // L0 frags: ((ot*11+ks)*64+l)*8+j
      int j = t & 7, l = (t >> 3) & 63, g = t >> 9;
      int ks = g % 11;
      int ot = g / 11;
      int k = 16 * ks + 8 * (l >> 5) + j;
      int n = ot * 32 + (l & 31);
      if (k < 100)      v = W0[(66 + k) * 128 + n];
      else if (k < 166) v = W0[(k - 100) * 128 + n];
      else              v = 0.0f;
    } else if (t < 71680) {          // L1-3 frags
      int u = t - 22528;
      int layer = u >> 14, r = u & 16383;
      int j = r & 7, l = (r >> 3) & 63, ks = (r >> 9) & 7, ot = r >> 12;
      int k = 16 * ks + 8 * (l >> 5) + j;
      int n = ot * 32 + (l & 31);
      const float* W = (layer == 0) ? W1 : (layer == 1) ? W2 : W3;
      v = W[k * 128 + n];
    } else {                         // packed W4: wt[W4OFF + qt*96 + kk*3 + e]
      int u2 = t - 71680;            // 0..383
      int qt = u2 / 96, r = u2 - 96 * qt;
      int kk = r / 3, e = r - 3 * kk;
      v = W4[(qt * 32 + kk) * 3 + e];
    }
    wt[t] = (_Float16)v;
  } else if (b < 282 + 28672) {      // ---- features f32 -> padded f16 ----
    int e = (b - 282) * 256 + threadIdx.x;
    int cell = e / 28, j4 = e - cell * 28;
    half4v o;
    if (j4 < 25) {
      f4 f = *(const f4*)(F + (size_t)cell * 100 + j4 * 4);
      o[0] = (_Float16)f[0]; o[1] = (_Float16)f[1];
      o[2] = (_Float16)f[2]; o[3] = (_Float16)f[3];
    } else {
      o[0] = o[1] = o[2] = o[3] = (_Float16)0.0f;
    }
    *(half4v*)(fout + (size_t)cell * CELL + j4 * 4) = o;
  } else if (hist != nullptr) {      // ---- histogram (hist pre-zeroed by memset) ----
    int i = (b - (282 + 28672)) * 256 + threadIdx.x;
    float2 uv = ((const float2*)UV)[i];
    int iU0 = (int)floorf(511.0f * uv.x);
    int iV0 = (int)floorf(511.0f * uv.y);
    atomicAdd(&hist[iU0 * 32 + (iV0 >> 4)], 1);
  }
}

__device__ __forceinline__ int point_bin(float U, float V) {
  int iU0 = (int)floorf(511.0f * U);
  int iV0 = (int)floorf(511.0f * V);
  return iU0 * 32 + (iV0 >> 4);
}

__global__ __launch_bounds__(256) void k_scanA(const int* __restrict__ hist,
                                               int* __restrict__ binoff,
                                               int* __restrict__ bsum) {
  __shared__ int s[256];
  int t = threadIdx.x, g = blockIdx.x * 256 + t;   // 64 blocks
  int v = hist[g];
  s[t] = v;
  __syncthreads();
  for (int d = 1; d < 256; d <<= 1) {
    int x = (t >= d) ? s[t - d] : 0;
    __syncthreads();
    s[t] += x;
    __syncthreads();
  }
  binoff[g] = s[t] - v;
  if (t == 255) bsum[blockIdx.x] = s[t];
}

__global__ __launch_bounds__(64) void k_scanB(const int* __restrict__ bsum,
                                              int* __restrict__ bbase) {
  __shared__ int s[64];
  int t = threadIdx.x;
  int v = bsum[t];
  s[t] = v;
  __syncthreads();
  for (int d = 1; d < 64; d <<= 1) {
    int x = (t >= d) ? s[t - d] : 0;
    __syncthreads();
    s[t] += x;
    __syncthreads();
  }
  bbase[t] = s[t] - v;
}

__global__ __launch_bounds__(256) void k_scatter(const float* __restrict__ UV,
                                                 int* __restrict__ binoff,
                                                 const int* __restrict__ bbase,
                                                 float4* __restrict__ sorted) {
  int i = blockIdx.x * 256 + threadIdx.x;     // 4096 blocks
  float2 uv = ((const float2*)UV)[i];
  int bin = point_bin(uv.x, uv.y);
  int pos = atomicAdd(&binoff[bin], 1) + bbase[bin >> 8];
  sorted[pos] = make_float4(uv.x, uv.y, __int_as_float(i), 0.0f);
}

// K=128 layer: A resident in regs; optionally prefetch next layer's A mid-loop.
// Zero-init acc, bias added at epilogue (first MFMA gated only by LDS).
template <bool PF>
__device__ __forceinline__ void layerPF(const half8 (&A)[8], half8 (&An)[8],
    const _Float16* __restrict__ wfn,
    const _Float16* Gin, _Float16* Gout, const float* __restrict__ bp,
    int lane, int nl, int kh, int ot) {
  f4 bf[4];
#pragma unroll
  for (int g = 0; g < 4; ++g)        // issued at phase start, used at epilogue
    bf[g] = *(const f4*)(bp + ot * 32 + 4 * kh + 8 * g);
  f16v a0, a1;
#pragma unroll
  for (int r = 0; r < 16; ++r) { a0[r] = 0.f; a1[r] = 0.f; }
#pragma unroll
  for (int ks = 0; ks < 4; ++ks) {
    half8 B0 = *(const half8*)(Gin + nl * STR1 + ks * 16 + kh * 8);
    half8 B1 = *(const half8*)(Gin + (32 + nl) * STR1 + ks * 16 + kh * 8);
    a0 = __builtin_amdgcn_mfma_f32_32x32x16_f16(A[ks], B0, a0, 0, 0, 0);
    a1 = __builtin_amdgcn_mfma_f32_32x32x16_f16(A[ks], B1, a1, 0, 0, 0);
  }
  if constexpr (PF) {                // prefetch next layer's A: 4 ksteps + epilogue
#pragma unroll                       // + barrier of slack to cover L2 latency
    for (int k2 = 0; k2 < 8; ++k2)
      An[k2] = *(const half8*)(wfn + ((ot * 8 + k2) * 64 + lane) * 8);
  }
#pragma unroll
  for (int ks = 4; ks < 8; ++ks) {
    half8 B0 = *(const half8*)(Gin + nl * STR1 + ks * 16 + kh * 8);
    half8 B1 = *(const half8*)(Gin + (32 + nl) * STR1 + ks * 16 + kh * 8);
    a0 = __builtin_amdgcn_mfma_f32_32x32x16_f16(A[ks], B0, a0, 0, 0, 0);
    a1 = __builtin_amdgcn_mfma_f32_32x32x16_f16(A[ks], B1, a1, 0, 0, 0);
  }
#pragma unroll
  for (int g = 0; g < 4; ++g) {
    half4v h0, h1;
#pragma unroll
    for (int i = 0; i < 4; ++i) {
      float z0 = a0[4 * g + i] + bf[g][i]; z0 = fmaxf(z0, 0.01f * z0);
      float z1 = a1[4 * g + i] + bf[g][i]; z1 = fmaxf(z1, 0.01f * z1);
      h0[i] = (_Float16)z0; h1[i] = (_Float16)z1;
    }
    int col = ot * 32 + 4 * kh + 8 * g;
    *(half4v*)(Gout + nl * STR1 + col) = h0;
    *(half4v*)(Gout + (32 + nl) * STR1 + col) = h1;
  }
}

// MODE: 1 = f16 features, unsorted; 2 = f16 + sorted
template <int MODE>
__global__ __launch_bounds__(256, 4) void k_main(
    const float* __restrict__ UV, const float4* __restrict__ sorted,
    const _Float16* __restrict__ wt, const _Float16* __restrict__ feat16,
    const float* __restrict__ b0, const float* __restrict__ b1,
    const float* __restrict__ b2, const float* __restrict__ b3,
    const float* __restrict__ b4, float* __restrict__ out) {
  __shared__ _Float16 bufA[TP * STR0] __attribute__((aligned(16)));  // 23552 B
  __shared__ _Float16 bufB[TP * STR1] __attribute__((aligned(16)));  // 17408 B
  const int t = threadIdx.x;
  const int lane = t & 63;
  const int q = t >> 6;        // wave id = out-quarter ot
  const int nl = lane & 31;
  const int kh = lane >> 5;
  const int ot = q;
  const int pFE = t >> 2;      // FE: 4 threads per point
  const int sFE = t & 3;

  // ---- L0 A-fragments: issued before the entire front-end (44 VGPR) ----
  half8 A0[11];
#pragma unroll
  for (int ks = 0; ks < 11; ++ks)
    A0[ks] = *(const half8*)(wt + ((ot * 11 + ks) * 64 + lane) * 8);
  half8 A1[8], A2[8], A3[8];   // filled by the pipeline below

  float U, V;
  int oidx;
  if constexpr (MODE == 2) {
    float4 s4 = sorted[blockIdx.x * TP + pFE];
    U = s4.x; V = s4.y; oidx = __float_as_int(s4.z);
  } else {
    oidx = blockIdx.x * TP + pFE;
    float2 uv = ((const float2*)UV)[oidx];
    U = uv.x; V = uv.y;
  }

  // ---------------- posenc (cols 100..165) + pad zero + oidx stash ----------
  if (sFE == 0) {
    bufA[pFE * STR0 + 100] = (_Float16)U;
    bufA[pFE * STR0 + 101] = (_Float16)V;
  }
  if (sFE == 1) {
#pragma unroll
    for (int c = 166; c < 176; ++c) bufA[pFE * STR0 + c] = (_Float16)0.0f;
  }
  if (sFE == 2) *(int*)&bufB[pFE * STR1 + 128] = oidx;  // layers write cols 0..127 only

  {
    const float inv2pi = 0.15915494309189535f;
    float Ur = U * inv2pi, Vr = V * inv2pi;
#pragma unroll
    for (int fi = 0; fi < 4; ++fi) {
      int f = 4 * fi + sFE;                  // 4 threads x 4 = 16 freqs
      float kk = (float)(1 << f);
      float ru = kk * Ur; ru -= floorf(ru);  // revolutions in [0,1)
      float rv = kk * Vr; rv -= floorf(rv);
      float su = __builtin_amdgcn_sinf(ru);  // v_sin_f32: sin(2*pi*x)
      float cu = __builtin_amdgcn_cosf(ru);
      float sv = __builtin_amdgcn_sinf(rv);
      float cv = __builtin_amdgcn_cosf(rv);
      int cbase = pFE * STR0 + 102 + 4 * f;
      bufA[cbase + 0] = (_Float16)su;
      bufA[cbase + 1] = (_Float16)sv;
      bufA[cbase + 2] = (_Float16)cu;
      bufA[cbase + 3] = (_Float16)cv;
    }
  }

  // ---------------- bilinear gather (cols 0..99), 4 threads/point ----------
  {
    float iu = 511.0f * U, iv = 511.0f * V;
    float fu0 = floorf(iu), fv0 = floorf(iv);
    int iU0 = (int)fu0, iV0 = (int)fv0;
    int iU1 = (int)ceilf(iu), iV1 = (int)ceilf(iv);
    float fu = iu - fu0, fv = iv - fv0;
    float w00 = (1.f - fu) * (1.f - fv);
    float w10 = fu * (1.f - fv);
    float w01 = (1.f - fu) * fv;
    float w11 = fu * fv;
    const half8* c00 = (const half8*)(feat16 + (size_t)(iU0 * GN + iV0) * CELL);
    const half8* c01 = (const half8*)(feat16 + (size_t)(iU0 * GN + iV1) * CELL);
    const half8* c10 = (const half8*)(feat16 + (size_t)(iU1 * GN + iV0) * CELL);
    const half8* c11 = (const half8*)(feat16 + (size_t)(iU1 * GN + iV1) * CELL);
    _Float16 h00 = (_Float16)w00, h01 = (_Float16)w01;
    _Float16 h10 = (_Float16)w10, h11 = (_Float16)w11;
    half8 v00, v01, v10, v11;
#pragma unroll
    for (int e = 0; e < 8; ++e) { v00[e]=h00; v01[e]=h01; v10[e]=h10; v11[e]=h11; }
    for (int j = sFE; j < 13; j += 4) {      // chunks {s, s+4, s+8, s+12}: covers 0..12
      half8 a = c00[j], b = c01[j], c = c10[j], d = c11[j];
      half8 o = a * v00 + b * v01 + c * v10 + d * v11;  // v_pk_fma_f16
      if (j < 12) {
        *(half8*)&bufA[pFE * STR0 + 8 * j] = o;
      } else {       // chunk 12: only cols 96..99 are real features
        half4v o4; o4[0]=o[0]; o4[1]=o[1]; o4[2]=o[2]; o4[3]=o[3];
        *(half4v*)&bufA[pFE * STR0 + 96] = o4;
      }
    }
  }
  __syncthreads();

  // ---------------- layer 0: K=176 (11 ksteps), bufA(STR0) -> bufB --------
  {
    f4 bf[4];
#pragma unroll
    for (int g = 0; g < 4; ++g)
      bf[g] = *(const f4*)(b0 + ot * 32 + 4 * kh + 8 * g);
    f16v a0, a1;
#pragma unroll
    for (int r = 0; r < 16; ++r) { a0[r] = 0.f; a1[r] = 0.f; }
#pragma unroll
    for (int ks = 0; ks < 8; ++ks) {
      half8 B0 = *(const half8*)&bufA[nl * STR0 + ks * 16 + kh * 8];
      half8 B1 = *(const half8*)&bufA[(32 + nl) * STR0 + ks * 16 + kh * 8];
      a0 = __builtin_amdgcn_mfma_f32_32x32x16_f16(A0[ks], B0, a0, 0, 0, 0);
      a1 = __builtin_amdgcn_mfma_f32_32x32x16_f16(A0[ks], B1, a1, 0, 0, 0);
    }
#pragma unroll                       // prefetch L1 A: A0 mostly dead (3 frags live)
    for (int k2 = 0; k2 < 8; ++k2)
      A1[k2] = *(const half8*)(wt + WOFF1 + ((ot * 8 + k2) * 64 + lane) * 8);
#pragma unroll
    for (int ks = 8; ks < 11; ++ks) {
      half8 B0 = *(const half8*)&bufA[nl * STR0 + ks * 16 + kh * 8];
      half8 B1 = *(const half8*)&bufA[(32 + nl) * STR0 + ks * 16 + kh * 8];
      a0 = __builtin_amdgcn_mfma_f32_32x32x16_f16(A0[ks], B0, a0, 0, 0, 0);
      a1 = __builtin_amdgcn_mfma_f32_32x32x16_f16(A0[ks], B1, a1, 0, 0, 0);
    }
#pragma unroll
    for (int g = 0; g < 4; ++g) {
      half4v h0, h1;
#pragma unroll
      for (int i = 0; i < 4; ++i) {
        float z0 = a0[4 * g + i] + bf[g][i]; z0 = fmaxf(z0, 0.01f * z0);
        float z1 = a1[4 * g + i] + bf[g][i]; z1 = fmaxf(z1, 0.01f * z1);
        h0[i] = (_Float16)z0; h1[i] = (_Float16)z1;
      }
      int col = ot * 32 + 4 * kh + 8 * g;
      *(half4v*)&bufB[nl * STR1 + col] = h0;
      *(half4v*)&bufB[(32 + nl) * STR1 + col] = h1;
    }
  }
  __syncthreads();
  layerPF<true >(A1, A2, wt + WOFF2, bufB, bufA, b1, lane, nl, kh, ot);
  __syncthreads();   // L1 done, A2 in flight/ready
  layerPF<true >(A2, A3, wt + WOFF3, bufA, bufB, b2, lane, nl, kh, ot);
  __syncthreads();   // L2 done, A3 ready
  layerPF<false>(A3, A3, wt,         bufB, bufA, b3, lane, nl, kh, ot);
  __syncthreads();   // L3 done -> bufA holds h3

  // ---------------- layer 4: 128 -> 3, 4 threads/point, packed f16 W4 -----
  {
    int pp = t >> 2, qt = t & 3;
    const _Float16* h4 = &bufA[pp * STR1 + qt * 32];
    const _Float16* w4 = wt + W4OFF + qt * 96;
    float y0 = 0.f, y1 = 0.f, y2 = 0.f;
#pragma unroll
    for (int c = 0; c < 4; ++c) {
      half8 hv = *(const half8*)(h4 + 8 * c);
      half8 wa = *(const half8*)(w4 + c * 24);
      half8 wb = *(const half8*)(w4 + c * 24 + 8);
      half8 wc = *(const half8*)(w4 + c * 24 + 16);
      _Float16 wf[24];
      *(half8*)&wf[0] = wa; *(half8*)&wf[8] = wb; *(half8*)&wf[16] = wc;
#pragma unroll
      for (int e8 = 0; e8 < 8; ++e8) {
        float vf = (float)hv[e8];
        y0 += vf * (float)wf[e8 * 3 + 0];
        y1 += vf * (float)wf[e8 * 3 + 1];
        y2 += vf * (float)wf[e8 * 3 + 2];
      }
    }
    y0 += __shfl_xor(y0, 1); y0 += __shfl_xor(y0, 2);
    y1 += __shfl_xor(y1, 1); y1 += __shfl_xor(y1, 2);
    y2 += __shfl_xor(y2, 1); y2 += __shfl_xor(y2, 2);
    if (qt == 0) {
      int op;
      if constexpr (MODE == 2) op = *(const int*)&bufB[pp * STR1 + 128];
      else                     op = blockIdx.x * TP + pp;
      out[(size_t)op * 3 + 0] = y0 + b4[0];
      out[(size_t)op * 3 + 1] = y1 + b4[1];
      out[(size_t)op * 3 + 2] = y2 + b4[2];
    }
  }
}

extern "C" void kernel_launch(void* const* d_in, const int* in_sizes, int n_in,
                              void* d_out, int out_size, void* d_ws, size_t ws_size,
                              hipStream_t stream) {
  const float* UV  = (const float*)d_in[0];
  const float* FEA = (const float*)d_in[1];
  const float* W0  = (const float*)d_in[2];
  const float* b0  = (const float*)d_in[3];
  const float* W1  = (const float*)d_in[4];
  const float* b1  = (const float*)d_in[5];
  const float* W2  = (const float*)d_in[6];
  const float* b2  = (const float*)d_in[7];
  const float* W3  = (const float*)d_in[8];
  const float* b3  = (const float*)d_in[9];
  const float* W4  = (const float*)d_in[10];
  const float* b4  = (const float*)d_in[11];
  float* out = (float*)d_out;

  char* ws = (char*)d_ws;
  _Float16* wt = (_Float16*)ws;
  int*    hist   = (int*)(ws + 147456);
  int*    binoff = (int*)(ws + 212992);
  int*    bsum   = (int*)(ws + 278528);
  int*    bbase  = (int*)(ws + 278784);
  float4* sorted = (float4*)(ws + 294912);
  _Float16* f16s = (_Float16*)(ws + 17072128);
  _Float16* f16u = (_Float16*)(ws + 147456);

  const size_t featBytes = (size_t)GN * GN * CELL * 2ull;   // 58,720,256
  const size_t needSort  = 17072128ull + featBytes;          // ~75.8 MB

  const int nblk = 1048576 / TP;   // 16384

  if (ws_size >= needSort) {
    hipMemsetAsync(hist, 0, 65536, stream);
    k_prep<<<282 + 28672 + 4096, 256, 0, stream>>>(W0, W1, W2, W3, W4, wt,
                                                   FEA, f16s, UV, hist);
    k_scanA<<<64, 256, 0, stream>>>(hist, binoff, bsum);
    k_scanB<<<1, 64, 0, stream>>>(bsum, bbase);
    k_scatter<<<4096, 256, 0, stream>>>(UV, binoff, bbase, sorted);
    k_main<2><<<nblk, 256, 0, stream>>>(UV, sorted, wt, f16s,
                                        b0, b1, b2, b3, b4, out);
  } else {
    k_prep<<<282 + 28672, 256, 0, stream>>>(W0, W1, W2, W3, W4, wt,
                                            FEA, f16u, UV, nullptr);
    k_main<1><<<nblk, 256, 0, stream>>>(UV, nullptr, wt, f16u,
                                        b0, b1, b2, b3, b4, out);
  }
}

// Round 6
// 495.227 us; speedup vs baseline: 2.1271x; 1.0112x over previous
//
#include <hip/hip_runtime.h>

// ReLU_Feat_Posenc: bilinear gather (512x512x100) + posenc(16 freq) + MLP 166->128x4->3
// R9: second bisect. R8 (= green R6 + f32-direct gather bundle) failed ~1.6e-2, same as
//     R7 => bug is in the f32 bundle, and inspection can't find an indexing error (error
//     magnitude says "slightly wrong values", not "wrong cells"). R9 keeps the aux win
//     (no f32->f16 pre-conversion pass) but makes k_main BIT-REPLICATE green R6's
//     arithmetic: load f32 cells, RTNE-cast each to f16 (same cast k_feat did), then the
//     IDENTICAL half8 f16 interp expression and identical stores. Chunk 12 loads only
//     cols 96..99 (never cols 100..103: last cell would read OOB; upper half zero like
//     feat16's padding). Everything else byte-identical to the Round-3 green kernel.
//     If this STILL fails -> the mechanical k_prep/launch changes are guilty -> revert.

#define GN    512
#define TP    64    // points per tile
#define STR0  184   // LDS X stride (f16), row = 368 B
#define STR1  136   // LDS G stride (f16), row = 272 B

// wt fragment-order offsets (f16 elems)
#define WOFF1 22528
#define WOFF2 38912
#define WOFF3 55296
#define W4OFF 71680  // packed W4: [qt 0..3][kk 0..31][e 0..2] f16 (384 elems)

typedef _Float16 half8  __attribute__((ext_vector_type(8)));
typedef _Float16 half4v __attribute__((ext_vector_type(4)));
typedef float    f4     __attribute__((ext_vector_type(4)));
typedef float    f16v   __attribute__((ext_vector_type(16)));

// ws layout (bytes):
//   0         wt fragment-order f16 (+ packed W4) (reserve 147456)
//   147456    hist    int[16384]
//   212992    binoff  int[16384]
//   278528    bsum    int[64]
//   278784    bbase   int[64]
//   294912    sorted  float4[1048576] (16 MB)   total ~17 MB

// ---------- fused prep: weights+W4 pack | hist ----------
__global__ __launch_bounds__(256) void k_prep(
    const float* __restrict__ W0, const float* __restrict__ W1,
    const float* __restrict__ W2, const float* __restrict__ W3,
    const float* __restrict__ W4, _Float16* __restrict__ wt,
    const float* __restrict__ UV, int* __restrict__ hist) {
  int b = blockIdx.x;
  if (b < 282) {                     // ---- weights into MFMA-fragment order ----
    int t = b * 256 + threadIdx.x;
    if (t >= 72064) return;
    float v;
    if (t < 22528) {                 // L0 frags: ((ot*11+ks)*64+l)*8+j
      int j = t & 7, l = (t >> 3) & 63, g = t >> 9;
      int ks = g % 11;
      int ot = g / 11;
      int k = 16 * ks + 8 * (l >> 5) + j;     // X column (R6 layout)
      int n = ot * 32 + (l & 31);             // out channel
      if (k < 100)      v = W0[(66 + k) * 128 + n];   // feat rows of W0
      else if (k < 166) v = W0[(k - 100) * 128 + n];  // UV + posenc rows
      else              v = 0.0f;                     // K pad 166..175
    } else if (t < 71680) {          // L1-3 frags
      int u = t - 22528;
      int layer = u >> 14, r = u & 16383;
      int j = r & 7, l = (r >> 3) & 63, ks = (r >> 9) & 7, ot = r >> 12;
      int k = 16 * ks + 8 * (l >> 5) + j;
      int n = ot * 32 + (l & 31);
      const float* W = (layer == 0) ? W1 : (layer == 1) ? W2 : W3;
      v = W[k * 128 + n];
    } else {                         // packed W4: wt[W4OFF + qt*96 + kk*3 + e]
      int u2 = t - 71680;            // 0..383
      int qt = u2 / 96, r = u2 - 96 * qt;
      int kk = r / 3, e = r - 3 * kk;
      v = W4[(qt * 32 + kk) * 3 + e];
    }
    wt[t] = (_Float16)v;
  } else if (hist != nullptr) {      // ---- histogram (hist pre-zeroed by memset) ----
    int i = (b - 282) * 256 + threadIdx.x;
    float2 uv = ((const float2*)UV)[i];
    int iU0 = (int)floorf(511.0f * uv.x);
    int iV0 = (int)floorf(511.0f * uv.y);
    atomicAdd(&hist[iU0 * 32 + (iV0 >> 4)], 1);
  }
}

__device__ __forceinline__ int point_bin(float U, float V) {
  int iU0 = (int)floorf(511.0f * U);
  int iV0 = (int)floorf(511.0f * V);
  return iU0 * 32 + (iV0 >> 4);
}

__global__ __launch_bounds__(256) void k_scanA(const int* __restrict__ hist,
                                               int* __restrict__ binoff,
                                               int* __restrict__ bsum) {
  __shared__ int s[256];
  int t = threadIdx.x, g = blockIdx.x * 256 + t;   // 64 blocks
  int v = hist[g];
  s[t] = v;
  __syncthreads();
  for (int d = 1; d < 256; d <<= 1) {
    int x = (t >= d) ? s[t - d] : 0;
    __syncthreads();
    s[t] += x;
    __syncthreads();
  }
  binoff[g] = s[t] - v;
  if (t == 255) bsum[blockIdx.x] = s[t];
}

__global__ __launch_bounds__(64) void k_scanB(const int* __restrict__ bsum,
                                              int* __restrict__ bbase) {
  __shared__ int s[64];
  int t = threadIdx.x;
  int v = bsum[t];
  s[t] = v;
  __syncthreads();
  for (int d = 1; d < 64; d <<= 1) {
    int x = (t >= d) ? s[t - d] : 0;
    __syncthreads();
    s[t] += x;
    __syncthreads();
  }
  bbase[t] = s[t] - v;
}

__global__ __launch_bounds__(256) void k_scatter(const float* __restrict__ UV,
                                                 int* __restrict__ binoff,
                                                 const int* __restrict__ bbase,
                                                 float4* __restrict__ sorted) {
  int i = blockIdx.x * 256 + threadIdx.x;     // 4096 blocks
  float2 uv = ((const float2*)UV)[i];
  int bin = point_bin(uv.x, uv.y);
  int pos = atomicAdd(&binoff[bin], 1) + bbase[bin >> 8];
  sorted[pos] = make_float4(uv.x, uv.y, __int_as_float(i), 0.0f);
}

// load 8 (or 4, zero-padded) f32s and RTNE-cast to f16 -- replicates k_feat's cast
__device__ __forceinline__ half8 ld8h(const float* __restrict__ p, bool full) {
  f4 lo = *(const f4*)p;
  f4 hi;
  if (full) hi = *(const f4*)(p + 4);
  else      { hi[0] = 0.f; hi[1] = 0.f; hi[2] = 0.f; hi[3] = 0.f; }
  half8 h;
  h[0] = (_Float16)lo[0]; h[1] = (_Float16)lo[1];
  h[2] = (_Float16)lo[2]; h[3] = (_Float16)lo[3];
  h[4] = (_Float16)hi[0]; h[5] = (_Float16)hi[1];
  h[6] = (_Float16)hi[2]; h[7] = (_Float16)hi[3];
  return h;
}

// K=128 layer: A resident in regs; optionally prefetch next layer's A mid-loop.
// Zero-init acc, bias added at epilogue (first MFMA gated only by LDS).
template <bool PF>
__device__ __forceinline__ void layerPF(const half8 (&A)[8], half8 (&An)[8],
    const _Float16* __restrict__ wfn,
    const _Float16* Gin, _Float16* Gout, const float* __restrict__ bp,
    int lane, int nl, int kh, int ot) {
  f4 bf[4];
#pragma unroll
  for (int g = 0; g < 4; ++g)        // issued at phase start, used at epilogue
    bf[g] = *(const f4*)(bp + ot * 32 + 4 * kh + 8 * g);
  f16v a0, a1;
#pragma unroll
  for (int r = 0; r < 16; ++r) { a0[r] = 0.f; a1[r] = 0.f; }
#pragma unroll
  for (int ks = 0; ks < 4; ++ks) {
    half8 B0 = *(const half8*)(Gin + nl * STR1 + ks * 16 + kh * 8);
    half8 B1 = *(const half8*)(Gin + (32 + nl) * STR1 + ks * 16 + kh * 8);
    a0 = __builtin_amdgcn_mfma_f32_32x32x16_f16(A[ks], B0, a0, 0, 0, 0);
    a1 = __builtin_amdgcn_mfma_f32_32x32x16_f16(A[ks], B1, a1, 0, 0, 0);
  }
  if constexpr (PF) {                // prefetch next layer's A under MFMA shadow
#pragma unroll
    for (int k2 = 0; k2 < 8; ++k2)
      An[k2] = *(const half8*)(wfn + ((ot * 8 + k2) * 64 + lane) * 8);
  }
#pragma unroll
  for (int ks = 4; ks < 8; ++ks) {
    half8 B0 = *(const half8*)(Gin + nl * STR1 + ks * 16 + kh * 8);
    half8 B1 = *(const half8*)(Gin + (32 + nl) * STR1 + ks * 16 + kh * 8);
    a0 = __builtin_amdgcn_mfma_f32_32x32x16_f16(A[ks], B0, a0, 0, 0, 0);
    a1 = __builtin_amdgcn_mfma_f32_32x32x16_f16(A[ks], B1, a1, 0, 0, 0);
  }
#pragma unroll
  for (int g = 0; g < 4; ++g) {
    half4v h0, h1;
#pragma unroll
    for (int i = 0; i < 4; ++i) {
      float z0 = a0[4 * g + i] + bf[g][i]; z0 = fmaxf(z0, 0.01f * z0);
      float z1 = a1[4 * g + i] + bf[g][i]; z1 = fmaxf(z1, 0.01f * z1);
      h0[i] = (_Float16)z0; h1[i] = (_Float16)z1;
    }
    int col = ot * 32 + 4 * kh + 8 * g;
    *(half4v*)(Gout + nl * STR1 + col) = h0;
    *(half4v*)(Gout + (32 + nl) * STR1 + col) = h1;
  }
}

// MODE: 1 = unsorted; 2 = sorted. f32 features, cast-to-f16 then R6's f16 interp.
template <int MODE>
__global__ __launch_bounds__(256, 4) void k_main(
    const float* __restrict__ UV, const float4* __restrict__ sorted,
    const _Float16* __restrict__ wt, const float* __restrict__ F,
    const float* __restrict__ b0, const float* __restrict__ b1,
    const float* __restrict__ b2, const float* __restrict__ b3,
    const float* __restrict__ b4, float* __restrict__ out) {
  __shared__ _Float16 bufA[TP * STR0] __attribute__((aligned(16)));  // 23552 B
  __shared__ _Float16 bufB[TP * STR1] __attribute__((aligned(16)));  // 17408 B
  const int t = threadIdx.x;
  const int lane = t & 63;
  const int nl = lane & 31;
  const int kh = lane >> 5;
  const int ot = t >> 6;       // wave id = out-quarter
  const int pFE = t >> 2;      // FE: 4 threads per point
  const int sFE = t & 3;

  // ---- L0 A-fragments issued up front ----
  half8 A0[11];
#pragma unroll
  for (int ks = 0; ks < 11; ++ks)
    A0[ks] = *(const half8*)(wt + ((ot * 11 + ks) * 64 + lane) * 8);
  half8 A1[8], A2[8], A3[8];   // filled by the pipeline below

  float U, V;
  int oidx;
  if constexpr (MODE == 2) {
    float4 s4 = sorted[blockIdx.x * TP + pFE];
    U = s4.x; V = s4.y; oidx = __float_as_int(s4.z);
  } else {
    oidx = blockIdx.x * TP + pFE;
    float2 uv = ((const float2*)UV)[oidx];
    U = uv.x; V = uv.y;
  }

  // ---------------- posenc (cols 100..165) + pad zero + oidx stash ----------
  if (sFE == 0) {
    bufA[pFE * STR0 + 100] = (_Float16)U;
    bufA[pFE * STR0 + 101] = (_Float16)V;
  }
  if (sFE == 1) {
#pragma unroll
    for (int c = 166; c < 176; ++c) bufA[pFE * STR0 + c] = (_Float16)0.0f;
  }
  if (sFE == 2) *(int*)&bufB[pFE * STR1 + 128] = oidx;  // layers write cols 0..127 only

  {
    const float inv2pi = 0.15915494309189535f;
    float Ur = U * inv2pi, Vr = V * inv2pi;
#pragma unroll
    for (int fi = 0; fi < 4; ++fi) {
      int f = 4 * fi + sFE;                  // 4 threads x 4 = 16 freqs
      float kk = (float)(1 << f);
      float ru = kk * Ur; ru -= floorf(ru);  // revolutions in [0,1)
      float rv = kk * Vr; rv -= floorf(rv);
      float su = __builtin_amdgcn_sinf(ru);  // v_sin_f32: sin(2*pi*x)
      float cu = __builtin_amdgcn_cosf(ru);
      float sv = __builtin_amdgcn_sinf(rv);
      float cv = __builtin_amdgcn_cosf(rv);
      int cbase = pFE * STR0 + 102 + 4 * f;
      bufA[cbase + 0] = (_Float16)su;
      bufA[cbase + 1] = (_Float16)sv;
      bufA[cbase + 2] = (_Float16)cu;
      bufA[cbase + 3] = (_Float16)cv;
    }
  }

  // ---- bilinear gather (cols 0..99): f32 load -> f16 cast -> R6's f16 interp ----
  {
    float iu = 511.0f * U, iv = 511.0f * V;
    float fu0 = floorf(iu), fv0 = floorf(iv);
    int iU0 = (int)fu0, iV0 = (int)fv0;
    int iU1 = (int)ceilf(iu), iV1 = (int)ceilf(iv);
    float fu = iu - fu0, fv = iv - fv0;
    float w00 = (1.f - fu) * (1.f - fv);
    float w10 = fu * (1.f - fv);
    float w01 = (1.f - fu) * fv;
    float w11 = fu * fv;
    const float* F00 = F + (size_t)(iU0 * GN + iV0) * 100;
    const float* F01 = F + (size_t)(iU0 * GN + iV1) * 100;
    const float* F10 = F + (size_t)(iU1 * GN + iV0) * 100;
    const float* F11 = F + (size_t)(iU1 * GN + iV1) * 100;
    _Float16 h00 = (_Float16)w00, h01 = (_Float16)w01;
    _Float16 h10 = (_Float16)w10, h11 = (_Float16)w11;
    half8 v00, v01, v10, v11;
#pragma unroll
    for (int e = 0; e < 8; ++e) { v00[e]=h00; v01[e]=h01; v10[e]=h10; v11[e]=h11; }
    for (int j = sFE; j < 13; j += 4) {      // chunks {s, s+4, s+8, s+12}: covers 0..12
      bool full = (j < 12);                  // chunk 12: only cols 96..99 exist
      half8 a = ld8h(F00 + 8 * j, full);
      half8 b = ld8h(F01 + 8 * j, full);
      half8 c = ld8h(F10 + 8 * j, full);
      half8 d = ld8h(F11 + 8 * j, full);
      half8 o = a * v00 + b * v01 + c * v10 + d * v11;  // v_pk_fma_f16 (as R6)
      if (full) {
        *(half8*)&bufA[pFE * STR0 + 8 * j] = o;
      } else {
        half4v o4; o4[0]=o[0]; o4[1]=o[1]; o4[2]=o[2]; o4[3]=o[3];
        *(half4v*)&bufA[pFE * STR0 + 96] = o4;
      }
    }
  }
  __syncthreads();

  // ---------------- layer 0: K=176 (11 ksteps), bufA(STR0) -> bufB --------
  {
    f4 bf[4];
#pragma unroll
    for (int g = 0; g < 4; ++g)
      bf[g] = *(const f4*)(b0 + ot * 32 + 4 * kh + 8 * g);
    f16v a0, a1;
#pragma unroll
    for (int r = 0; r < 16; ++r) { a0[r] = 0.f; a1[r] = 0.f; }
#pragma unroll
    for (int ks = 0; ks < 8; ++ks) {
      half8 B0 = *(const half8*)&bufA[nl * STR0 + ks * 16 + kh * 8];
      half8 B1 = *(const half8*)&bufA[(32 + nl) * STR0 + ks * 16 + kh * 8];
      a0 = __builtin_amdgcn_mfma_f32_32x32x16_f16(A0[ks], B0, a0, 0, 0, 0);
      a1 = __builtin_amdgcn_mfma_f32_32x32x16_f16(A0[ks], B1, a1, 0, 0, 0);
    }
#pragma unroll                       // prefetch L1 A under the MFMA shadow
    for (int k2 = 0; k2 < 8; ++k2)
      A1[k2] = *(const half8*)(wt + WOFF1 + ((ot * 8 + k2) * 64 + lane) * 8);
#pragma unroll
    for (int ks = 8; ks < 11; ++ks) {
      half8 B0 = *(const half8*)&bufA[nl * STR0 + ks * 16 + kh * 8];
      half8 B1 = *(const half8*)&bufA[(32 + nl) * STR0 + ks * 16 + kh * 8];
      a0 = __builtin_amdgcn_mfma_f32_32x32x16_f16(A0[ks], B0, a0, 0, 0, 0);
      a1 = __builtin_amdgcn_mfma_f32_32x32x16_f16(A0[ks], B1, a1, 0, 0, 0);
    }
#pragma unroll
    for (int g = 0; g < 4; ++g) {
      half4v h0, h1;
#pragma unroll
      for (int i = 0; i < 4; ++i) {
        float z0 = a0[4 * g + i] + bf[g][i]; z0 = fmaxf(z0, 0.01f * z0);
        float z1 = a1[4 * g + i] + bf[g][i]; z1 = fmaxf(z1, 0.01f * z1);
        h0[i] = (_Float16)z0; h1[i] = (_Float16)z1;
      }
      int col = ot * 32 + 4 * kh + 8 * g;
      *(half4v*)&bufB[nl * STR1 + col] = h0;
      *(half4v*)&bufB[(32 + nl) * STR1 + col] = h1;
    }
  }
  __syncthreads();
  layerPF<true >(A1, A2, wt + WOFF2, bufB, bufA, b1, lane, nl, kh, ot);
  __syncthreads();   // L1 done, A2 ready
  layerPF<true >(A2, A3, wt + WOFF3, bufA, bufB, b2, lane, nl, kh, ot);
  __syncthreads();   // L2 done, A3 ready
  layerPF<false>(A3, A3, wt,         bufB, bufA, b3, lane, nl, kh, ot);
  __syncthreads();   // L3 done -> bufA holds h3

  // ---------------- layer 4: 128 -> 3, 4 threads/point, packed f16 W4 -------
  {
    int pp = t >> 2, qt = t & 3;
    const _Float16* h4 = &bufA[pp * STR1 + qt * 32];
    const _Float16* w4 = wt + W4OFF + qt * 96;
    float y0 = 0.f, y1 = 0.f, y2 = 0.f;
#pragma unroll
    for (int c = 0; c < 4; ++c) {
      half8 hv = *(const half8*)(h4 + 8 * c);
      half8 wa = *(const half8*)(w4 + c * 24);
      half8 wb = *(const half8*)(w4 + c * 24 + 8);
      half8 wc = *(const half8*)(w4 + c * 24 + 16);
      _Float16 wf[24];
      *(half8*)&wf[0] = wa; *(half8*)&wf[8] = wb; *(half8*)&wf[16] = wc;
#pragma unroll
      for (int e8 = 0; e8 < 8; ++e8) {
        float vf = (float)hv[e8];
        y0 += vf * (float)wf[e8 * 3 + 0];
        y1 += vf * (float)wf[e8 * 3 + 1];
        y2 += vf * (float)wf[e8 * 3 + 2];
      }
    }
    y0 += __shfl_xor(y0, 1); y0 += __shfl_xor(y0, 2);
    y1 += __shfl_xor(y1, 1); y1 += __shfl_xor(y1, 2);
    y2 += __shfl_xor(y2, 1); y2 += __shfl_xor(y2, 2);
    if (qt == 0) {
      int op;
      if constexpr (MODE == 2) op = *(const int*)&bufB[pp * STR1 + 128];
      else                     op = blockIdx.x * TP + pp;
      out[(size_t)op * 3 + 0] = y0 + b4[0];
      out[(size_t)op * 3 + 1] = y1 + b4[1];
      out[(size_t)op * 3 + 2] = y2 + b4[2];
    }
  }
}

extern "C" void kernel_launch(void* const* d_in, const int* in_sizes, int n_in,
                              void* d_out, int out_size, void* d_ws, size_t ws_size,
                              hipStream_t stream) {
  const float* UV  = (const float*)d_in[0];
  const float* FEA = (const float*)d_in[1];
  const float* W0  = (const float*)d_in[2];
  const float* b0  = (const float*)d_in[3];
  const float* W1  = (const float*)d_in[4];
  const float* b1  = (const float*)d_in[5];
  const float* W2  = (const float*)d_in[6];
  const float* b2  = (const float*)d_in[7];
  const float* W3  = (const float*)d_in[8];
  const float* b3  = (const float*)d_in[9];
  const float* W4  = (const float*)d_in[10];
  const float* b4  = (const float*)d_in[11];
  float* out = (float*)d_out;

  char* ws = (char*)d_ws;
  _Float16* wt = (_Float16*)ws;
  int*    hist   = (int*)(ws + 147456);
  int*    binoff = (int*)(ws + 212992);
  int*    bsum   = (int*)(ws + 278528);
  int*    bbase  = (int*)(ws + 278784);
  float4* sorted = (float4*)(ws + 294912);

  const size_t needSort = 294912ull + 16777216ull;   // ~17 MB

  const int nblk = 1048576 / TP;   // 16384

  if (ws_size >= needSort) {
    hipMemsetAsync(hist, 0, 65536, stream);
    k_prep<<<282 + 4096, 256, 0, stream>>>(W0, W1, W2, W3, W4, wt, UV, hist);
    k_scanA<<<64, 256, 0, stream>>>(hist, binoff, bsum);
    k_scanB<<<1, 64, 0, stream>>>(bsum, bbase);
    k_scatter<<<4096, 256, 0, stream>>>(UV, binoff, bbase, sorted);
    k_main<2><<<nblk, 256, 0, stream>>>(UV, sorted, wt, FEA,
                                        b0, b1, b2, b3, b4, out);
  } else {
    k_prep<<<282, 256, 0, stream>>>(W0, W1, W2, W3, W4, wt, UV, nullptr);
    k_main<1><<<nblk, 256, 0, stream>>>(UV, nullptr, wt, FEA,
                                        b0, b1, b2, b3, b4, out);
  }
}